// Round 22
// baseline (225.371 us; speedup 1.0000x reference)
//
#include <hip/hip_runtime.h>
#include <hip/hip_bf16.h>

// out[m,b,:] = kv[m,b,:] @ W + bo + query[b,:],  W = (Wo@Wv) row o, col d
// (softmax over size-1 axis == 1 -> ones; q/k/Wq/Wk dead). f32 output.
// K1: Cw = Wo@Wv, MFMA bf16 (proven r9). ~3us.
// K2: single-pass GEMM, NO prepass (saves 37us kernel + 14us gaps + 134MB
//     HBM round-trip): A staged as f32 via glds (r15's row&7 swizzle) into
//     the r19/r21-proven 3-stage counted-vmcnt pipeline (BK=32, 128x128,
//     2x2 waves, cvt8 in compute — all individually proven). 72KB LDS ->
//     2 blocks/CU (= r21's effective occupancy).

typedef __attribute__((ext_vector_type(4))) float f32x4;
typedef __attribute__((ext_vector_type(8))) short short8;

#define D_MODEL 1024
#define BATCH   4096
#define M_ROWS  32768   // 8 * 4096

__device__ __forceinline__ short f2bf(float f) {
    union { float f; unsigned u; } x; x.f = f;
    unsigned r = (x.u + 0x7fffu + ((x.u >> 16) & 1u)) >> 16;   // RNE
    return (short)r;
}

__device__ __forceinline__ unsigned bfpk(float lo, float hi) {
    __hip_bfloat162 h = __float22bfloat162_rn(make_float2(lo, hi));  // v_cvt_pk_bf16_f32
    unsigned u; __builtin_memcpy(&u, &h, 4); return u;
}

__device__ __forceinline__ short8 cvt8(float4 a, float4 b) {
    union { unsigned u[4]; short8 s; } r;
    r.u[0] = bfpk(a.x, a.y);
    r.u[1] = bfpk(a.z, a.w);
    r.u[2] = bfpk(b.x, b.y);
    r.u[3] = bfpk(b.z, b.w);
    return r.s;
}

// ---------------- Kernel 1: fuse weights Cw = Wo @ Wv (bf16, MFMA, 64x64) ----------------
__global__ __launch_bounds__(256) void fuse_w_kernel(
        const float* __restrict__ Wo, const float* __restrict__ Wv,
        short* __restrict__ Cw) {
    __shared__ __align__(16) short Ash[64][32];
    __shared__ __align__(16) short Bsh[64][32];
    const int t = threadIdx.x;
    const int lane = t & 63;
    const int w = t >> 6;
    const int wr = w >> 1, wc = w & 1;
    const int brow = blockIdx.y * 64;   // o
    const int bcol = blockIdx.x * 64;   // d

    f32x4 acc[2][2];
#pragma unroll
    for (int m = 0; m < 2; ++m)
#pragma unroll
        for (int n = 0; n < 2; ++n) acc[m][n] = (f32x4)(0.0f);

    for (int kt = 0; kt < 32; ++kt) {
        const float* ga = Wo + (size_t)(brow + (t >> 2)) * D_MODEL + kt * 32 + (t & 3) * 8;
        float4 a0 = *(const float4*)ga;
        float4 a1 = *(const float4*)(ga + 4);
        float4 bv[2];
#pragma unroll
        for (int j = 0; j < 2; ++j) {
            int lin = j * 256 + t;
            int e = lin >> 4, c4 = lin & 15;
            bv[j] = *(const float4*)(Wv + (size_t)(kt * 32 + e) * D_MODEL + bcol + c4 * 4);
        }
        *reinterpret_cast<short8*>(&Ash[t >> 2][(t & 3) * 8]) = cvt8(a0, a1);
#pragma unroll
        for (int j = 0; j < 2; ++j) {
            int lin = j * 256 + t;
            int e = lin >> 4, c4 = lin & 15;
            int d = c4 * 4;
            Bsh[d + 0][e] = f2bf(bv[j].x);
            Bsh[d + 1][e] = f2bf(bv[j].y);
            Bsh[d + 2][e] = f2bf(bv[j].z);
            Bsh[d + 3][e] = f2bf(bv[j].w);
        }
        __syncthreads();
        {
            const int r = lane & 15, q = lane >> 4;
            short8 af[2], bfr[2];
#pragma unroll
            for (int m = 0; m < 2; ++m)
                af[m] = *reinterpret_cast<const short8*>(&Ash[wr * 32 + m * 16 + r][q * 8]);
#pragma unroll
            for (int n = 0; n < 2; ++n)
                bfr[n] = *reinterpret_cast<const short8*>(&Bsh[wc * 32 + n * 16 + r][q * 8]);
#pragma unroll
            for (int m = 0; m < 2; ++m)
#pragma unroll
                for (int n = 0; n < 2; ++n)
                    acc[m][n] = __builtin_amdgcn_mfma_f32_16x16x32_bf16(
                        af[m], bfr[n], acc[m][n], 0, 0, 0);
        }
        __syncthreads();
    }

    const int r = lane & 15, q = lane >> 4;
#pragma unroll
    for (int m = 0; m < 2; ++m)
#pragma unroll
        for (int n = 0; n < 2; ++n)
#pragma unroll
            for (int j = 0; j < 4; ++j) {
                int o = brow + wr * 32 + m * 16 + q * 4 + j;
                int d = bcol + wc * 32 + n * 16 + r;
                Cw[(size_t)o * D_MODEL + d] = f2bf(acc[m][n][j]);
            }
}

// ---------------- Kernel 2: f32-A direct, 128x128 / 2x2 waves / 3-stage counted vmcnt ----------------
__global__ __launch_bounds__(256, 2) void attn_gemm_kernel(
        const float* __restrict__ kv, const float* __restrict__ query,
        const short* __restrict__ Cw, const float* __restrict__ bo,
        float* __restrict__ out) {
    // A: 128x32 f32 = 16KB/stage (4 glds/thr), XOR swizzle chunk^=(row&7)
    //    (r15-proven; 2-way residual = free). B: 128x32 bf16 = 8KB/stage
    //    (2 glds/thr), chunk^=((row>>1)&3) (r21-proven, 0 conflicts).
    // 3 stages = 72KB. Counted vmcnt keeps 2 future tiles in flight.
    __shared__ __align__(16) float Afs[3][128][32];
    __shared__ __align__(16) short Bsh[3][128][32];
    const int t = threadIdx.x;
    const int lane = t & 63;
    const int w = t >> 6;                    // 4 waves
    const int wm = w >> 1, wn = w & 1;       // 2 x 2 wave grid
    const int r = lane & 15, q = lane >> 4;

    // XCD swizzle (proven r8): the 8 o-tiles of one row-tile share L%8.
    const int L = blockIdx.x;
    const int x = L & 7, j5 = L >> 3;
    const int bx = j5 & 7;                   // o-tile (0..7)
    const int rt = (j5 >> 3) * 8 + x;        // row-tile (0..255)
    const int brow = rt * 128;

    f32x4 acc[4][4];
#pragma unroll
    for (int m = 0; m < 4; ++m)
#pragma unroll
        for (int n = 0; n < 4; ++n) acc[m][n] = (f32x4)(0.0f);

    auto stage = [&](int kt, int buf) {      // 6 glds/thread, no VGPR results
#pragma unroll
        for (int i = 0; i < 4; ++i) {        // A: 16KB = 1024 chunks, 4 issues
            int chunk = i * 256 + t;
            int rl = chunk >> 3, d = chunk & 7;
            int cs = d ^ (rl & 7);
            const float* g = kv + (size_t)(brow + rl) * D_MODEL + kt * 32 + cs * 4;
            __builtin_amdgcn_global_load_lds(
                (const __attribute__((address_space(1))) void*)g,
                (__attribute__((address_space(3))) void*)
                    ((char*)&Afs[buf][0][0] + i * 4096 + w * 1024),
                16, 0, 0);
        }
#pragma unroll
        for (int i = 0; i < 2; ++i) {        // B: 8KB = 512 chunks, 2 issues
            int chunk = i * 256 + t;
            int rl = chunk >> 2, d = chunk & 3;
            int cs = d ^ ((rl >> 1) & 3);
            const short* g = Cw + (size_t)(bx * 128 + rl) * D_MODEL + kt * 32 + cs * 8;
            __builtin_amdgcn_global_load_lds(
                (const __attribute__((address_space(1))) void*)g,
                (__attribute__((address_space(3))) void*)
                    ((char*)&Bsh[buf][0][0] + i * 4096 + w * 1024),
                16, 0, 0);
        }
    };
    auto compute = [&](int buf) {
        short8 af[4], bfr[4];
#pragma unroll
        for (int m = 0; m < 4; ++m) {
            int row = wm * 64 + m * 16 + r;
            int c0 = (2 * q) ^ (row & 7);
            int c1 = (2 * q + 1) ^ (row & 7);
            float4 lo = *(const float4*)&Afs[buf][row][c0 * 4];
            float4 hi = *(const float4*)&Afs[buf][row][c1 * 4];
            af[m] = cvt8(lo, hi);                 // pk cvt under MFMA (r15-proven)
        }
#pragma unroll
        for (int n = 0; n < 4; ++n) {
            int row = wn * 64 + n * 16 + r;
            int c = q ^ ((row >> 1) & 3);
            bfr[n] = *reinterpret_cast<const short8*>(&Bsh[buf][row][c * 8]);
        }
#pragma unroll
        for (int m = 0; m < 4; ++m)
#pragma unroll
            for (int n = 0; n < 4; ++n)
                acc[m][n] = __builtin_amdgcn_mfma_f32_16x16x32_bf16(
                    af[m], bfr[n], acc[m][n], 0, 0, 0);
    };

    // prologue: tiles 0,1 in flight (12 glds/thread)
    stage(0, 0);
    stage(1, 1);
    for (int kt = 0; kt < 32; ++kt) {
        const int bsel = kt % 3;
        if (kt < 30) {
            stage(kt + 2, (kt + 2) % 3);     // 18 outstanding max
            asm volatile("s_waitcnt vmcnt(12)" ::: "memory");  // kt's 6 landed
        } else if (kt == 30) {
            asm volatile("s_waitcnt vmcnt(6)" ::: "memory");
        } else {
            asm volatile("s_waitcnt vmcnt(0)" ::: "memory");
        }
        __builtin_amdgcn_s_barrier();        // all waves' kt-writes visible
        compute(bsel);                       // kt+1, kt+2 glds still flying
        __builtin_amdgcn_s_barrier();        // reads done before buf reuse
    }

    // epilogue: + bo + query residual, f32 store
#pragma unroll
    for (int n = 0; n < 4; ++n) {
        int o = bx * 128 + wn * 64 + n * 16 + r;
        float bov = bo[o];
#pragma unroll
        for (int m = 0; m < 4; ++m) {
            int gb = brow + wm * 64 + m * 16 + q * 4;
#pragma unroll
            for (int j = 0; j < 4; ++j) {
                int grow = gb + j;
                out[(size_t)grow * D_MODEL + o] =
                    acc[m][n][j] + bov +
                    query[(size_t)(grow & (BATCH - 1)) * D_MODEL + o];
            }
        }
    }
}

extern "C" void kernel_launch(void* const* d_in, const int* in_sizes, int n_in,
                              void* d_out, int out_size, void* d_ws, size_t ws_size,
                              hipStream_t stream) {
    int kv_i = 1, q_i = 0, bo_i = 6;
    int w_i[4] = {2, 3, 4, 5};
    int nw = 0;
    for (int i = 0; i < n_in; ++i) {
        long s = in_sizes[i];
        if (s == 33554432) kv_i = i;
        else if (s == 4194304) q_i = i;
        else if (s == 1024) bo_i = i;
        else if (s == 1048576 && nw < 4) w_i[nw++] = i;
    }
    const float* query = (const float*)d_in[q_i];
    const float* kv    = (const float*)d_in[kv_i];
    const float* Wv    = (const float*)d_in[w_i[2]];
    const float* Wo    = (const float*)d_in[w_i[3]];
    const float* bo    = (const float*)d_in[bo_i];
    short* Cw  = (short*)d_ws;              // 1024*1024 bf16 = 2 MB
    float* out = (float*)d_out;             // f32 output

    fuse_w_kernel<<<dim3(16, 16), dim3(256), 0, stream>>>(Wo, Wv, Cw);
    attn_gemm_kernel<<<dim3(2048), dim3(256), 0, stream>>>(kv, query, Cw, bo, out);
}

// Round 23
// 179.970 us; speedup vs baseline: 1.2523x; 1.2523x over previous
//
#include <hip/hip_runtime.h>
#include <hip/hip_bf16.h>

// out[m,b,:] = kv[m,b,:] @ W + bo + query[b,:],  W = (Wo@Wv) row o, col d
// (softmax over size-1 axis == 1 -> ones; q/k/Wq/Wk dead). f32 output.
// PRE (merged): blocks 0..255 = fuse_w (Cw = Wo@Wv, MFMA, proven r9);
//               blocks 256..2303 = kv f32->bf16 cvt. One launch fewer.
// K2 (bf16): r21 config (128x128, BK=32, 2x2 waves, swizzle (row>>1)&3,
//     XCD swizzle, counted vmcnt) but 2-STAGE LDS (32KB): occupancy 2->~5
//     blocks/CU; r22 proved occupancy >> pipeline depth here.
// Fallback (ws < 69.2MB): r15 f32 kernel verbatim.

typedef __attribute__((ext_vector_type(4))) float f32x4;
typedef __attribute__((ext_vector_type(8))) short short8;

#define D_MODEL 1024
#define BATCH   4096
#define M_ROWS  32768   // 8 * 4096

__device__ __forceinline__ short f2bf(float f) {
    union { float f; unsigned u; } x; x.f = f;
    unsigned r = (x.u + 0x7fffu + ((x.u >> 16) & 1u)) >> 16;   // RNE
    return (short)r;
}

__device__ __forceinline__ unsigned bfpk(float lo, float hi) {
    __hip_bfloat162 h = __float22bfloat162_rn(make_float2(lo, hi));  // v_cvt_pk_bf16_f32
    unsigned u; __builtin_memcpy(&u, &h, 4); return u;
}

__device__ __forceinline__ short8 cvt8(float4 a, float4 b) {
    union { unsigned u[4]; short8 s; } r;
    r.u[0] = bfpk(a.x, a.y);
    r.u[1] = bfpk(a.z, a.w);
    r.u[2] = bfpk(b.x, b.y);
    r.u[3] = bfpk(b.z, b.w);
    return r.s;
}

// ---------------- Merged prepass: fuse_w (blocks 0..255) + kv cvt (256..2303) ----------------
__global__ __launch_bounds__(256) void pre_kernel(
        const float* __restrict__ Wo, const float* __restrict__ Wv,
        short* __restrict__ Cw,
        const float* __restrict__ kv, short* __restrict__ kvb) {
    const int t = threadIdx.x;
    if (blockIdx.x >= 256) {
        // ---- kv f32 -> bf16, grid-stride over 2048 effective blocks
        const long n8 = (long)M_ROWS * D_MODEL / 8;
        long i = (long)(blockIdx.x - 256) * 256 + t;
        const long stride = 2048L * 256;
        for (; i < n8; i += stride) {
            const float4* p = (const float4*)(kv + i * 8);
            float4 a = p[0], b = p[1];
            *reinterpret_cast<short8*>(kvb + i * 8) = cvt8(a, b);
        }
        return;
    }
    // ---- fuse_w: Cw = Wo @ Wv (64x64 tile; grid 16x16 flattened)
    __shared__ __align__(16) short Ash[64][32];
    __shared__ __align__(16) short Bsh[64][32];
    const int lane = t & 63;
    const int w = t >> 6;
    const int wr = w >> 1, wc = w & 1;
    const int brow = (blockIdx.x >> 4) * 64;   // o
    const int bcol = (blockIdx.x & 15) * 64;   // d

    f32x4 acc[2][2];
#pragma unroll
    for (int m = 0; m < 2; ++m)
#pragma unroll
        for (int n = 0; n < 2; ++n) acc[m][n] = (f32x4)(0.0f);

    for (int kt = 0; kt < 32; ++kt) {
        const float* ga = Wo + (size_t)(brow + (t >> 2)) * D_MODEL + kt * 32 + (t & 3) * 8;
        float4 a0 = *(const float4*)ga;
        float4 a1 = *(const float4*)(ga + 4);
        float4 bv[2];
#pragma unroll
        for (int j = 0; j < 2; ++j) {
            int lin = j * 256 + t;
            int e = lin >> 4, c4 = lin & 15;
            bv[j] = *(const float4*)(Wv + (size_t)(kt * 32 + e) * D_MODEL + bcol + c4 * 4);
        }
        *reinterpret_cast<short8*>(&Ash[t >> 2][(t & 3) * 8]) = cvt8(a0, a1);
#pragma unroll
        for (int j = 0; j < 2; ++j) {
            int lin = j * 256 + t;
            int e = lin >> 4, c4 = lin & 15;
            int d = c4 * 4;
            Bsh[d + 0][e] = f2bf(bv[j].x);
            Bsh[d + 1][e] = f2bf(bv[j].y);
            Bsh[d + 2][e] = f2bf(bv[j].z);
            Bsh[d + 3][e] = f2bf(bv[j].w);
        }
        __syncthreads();
        {
            const int r = lane & 15, q = lane >> 4;
            short8 af[2], bfr[2];
#pragma unroll
            for (int m = 0; m < 2; ++m)
                af[m] = *reinterpret_cast<const short8*>(&Ash[wr * 32 + m * 16 + r][q * 8]);
#pragma unroll
            for (int n = 0; n < 2; ++n)
                bfr[n] = *reinterpret_cast<const short8*>(&Bsh[wc * 32 + n * 16 + r][q * 8]);
#pragma unroll
            for (int m = 0; m < 2; ++m)
#pragma unroll
                for (int n = 0; n < 2; ++n)
                    acc[m][n] = __builtin_amdgcn_mfma_f32_16x16x32_bf16(
                        af[m], bfr[n], acc[m][n], 0, 0, 0);
        }
        __syncthreads();
    }

    const int r = lane & 15, q = lane >> 4;
#pragma unroll
    for (int m = 0; m < 2; ++m)
#pragma unroll
        for (int n = 0; n < 2; ++n)
#pragma unroll
            for (int j = 0; j < 4; ++j) {
                int o = brow + wr * 32 + m * 16 + q * 4 + j;
                int d = bcol + wc * 32 + n * 16 + r;
                Cw[(size_t)o * D_MODEL + d] = f2bf(acc[m][n][j]);
            }
}

// ---------------- Kernel 2 (bf16): 128x128 / 2x2 waves / 2-stage counted vmcnt ----------------
__global__ __launch_bounds__(256, 4) void attn_gemm_bf16(
        const short* __restrict__ kvb, const float* __restrict__ query,
        const short* __restrict__ Cw, const float* __restrict__ bo,
        float* __restrict__ out) {
    // Per K-tile (BK=32): A 128x32 bf16 = 8KB (2 glds/thr), B same.
    // 2 stages = 32KB -> ~5 blocks/CU. Swizzle chunk^=(row>>1)&3 both-sides
    // (0 conflicts, r20/r21-proven). Counted vmcnt(4): kt+1's 4 glds stay
    // in flight across both barriers.
    __shared__ __align__(16) short Afs[2][128][32];
    __shared__ __align__(16) short Bsh[2][128][32];
    const int t = threadIdx.x;
    const int lane = t & 63;
    const int w = t >> 6;                    // 4 waves
    const int wm = w >> 1, wn = w & 1;       // 2 x 2 wave grid
    const int r = lane & 15, q = lane >> 4;

    // XCD swizzle (proven r8): the 8 o-tiles of one row-tile share L%8.
    const int L = blockIdx.x;
    const int x = L & 7, j5 = L >> 3;
    const int bx = j5 & 7;                   // o-tile (0..7)
    const int rt = (j5 >> 3) * 8 + x;        // row-tile (0..255)
    const int brow = rt * 128;

    f32x4 acc[4][4];
#pragma unroll
    for (int m = 0; m < 4; ++m)
#pragma unroll
        for (int n = 0; n < 4; ++n) acc[m][n] = (f32x4)(0.0f);

    auto stage = [&](int kt, int buf) {      // 4 glds/thread, no VGPR results
#pragma unroll
        for (int i = 0; i < 2; ++i) {        // A: 8KB = 512 chunks, 2 issues
            int chunk = i * 256 + t;
            int rl = chunk >> 2, d = chunk & 3;
            int cs = d ^ ((rl >> 1) & 3);
            const short* g = kvb + (size_t)(brow + rl) * D_MODEL + kt * 32 + cs * 8;
            __builtin_amdgcn_global_load_lds(
                (const __attribute__((address_space(1))) void*)g,
                (__attribute__((address_space(3))) void*)
                    ((char*)&Afs[buf][0][0] + i * 4096 + w * 1024),
                16, 0, 0);
        }
#pragma unroll
        for (int i = 0; i < 2; ++i) {        // B: 8KB, 2 issues
            int chunk = i * 256 + t;
            int rl = chunk >> 2, d = chunk & 3;
            int cs = d ^ ((rl >> 1) & 3);
            const short* g = Cw + (size_t)(bx * 128 + rl) * D_MODEL + kt * 32 + cs * 8;
            __builtin_amdgcn_global_load_lds(
                (const __attribute__((address_space(1))) void*)g,
                (__attribute__((address_space(3))) void*)
                    ((char*)&Bsh[buf][0][0] + i * 4096 + w * 1024),
                16, 0, 0);
        }
    };
    auto compute = [&](int buf) {
        short8 af[4], bfr[4];
#pragma unroll
        for (int m = 0; m < 4; ++m) {
            int row = wm * 64 + m * 16 + r;
            int c = q ^ ((row >> 1) & 3);
            af[m] = *reinterpret_cast<const short8*>(&Afs[buf][row][c * 8]);
        }
#pragma unroll
        for (int n = 0; n < 4; ++n) {
            int row = wn * 64 + n * 16 + r;
            int c = q ^ ((row >> 1) & 3);
            bfr[n] = *reinterpret_cast<const short8*>(&Bsh[buf][row][c * 8]);
        }
#pragma unroll
        for (int m = 0; m < 4; ++m)
#pragma unroll
            for (int n = 0; n < 4; ++n)
                acc[m][n] = __builtin_amdgcn_mfma_f32_16x16x32_bf16(
                    af[m], bfr[n], acc[m][n], 0, 0, 0);
    };

    // prologue: tile 0 in flight
    stage(0, 0);
    for (int kt = 0; kt < 32; ++kt) {
        const int cur = kt & 1;
        if (kt < 31) {
            stage(kt + 1, cur ^ 1);          // 8 outstanding max
            asm volatile("s_waitcnt vmcnt(4)" ::: "memory");   // kt's 4 landed
        } else {
            asm volatile("s_waitcnt vmcnt(0)" ::: "memory");
        }
        __builtin_amdgcn_s_barrier();        // all waves' kt-writes visible
        compute(cur);                        // kt+1 glds still flying
        __builtin_amdgcn_s_barrier();        // reads done before buf reuse
    }

    // epilogue: + bo + query residual, f32 store
#pragma unroll
    for (int n = 0; n < 4; ++n) {
        int o = bx * 128 + wn * 64 + n * 16 + r;
        float bov = bo[o];
#pragma unroll
        for (int m = 0; m < 4; ++m) {
            int gb = brow + wm * 64 + m * 16 + q * 4;
#pragma unroll
            for (int j = 0; j < 4; ++j) {
                int grow = gb + j;
                out[(size_t)grow * D_MODEL + o] =
                    acc[m][n][j] + bov +
                    query[(size_t)(grow & (BATCH - 1)) * D_MODEL + o];
            }
        }
    }
}

// ---------------- Kernel 2 fallback (f32 A): r15 verbatim ----------------
__global__ __launch_bounds__(256, 4) void attn_gemm_f32(
        const float* __restrict__ kv, const float* __restrict__ query,
        const short* __restrict__ Cw, const float* __restrict__ bo,
        float* __restrict__ out) {
    __shared__ __align__(16) float Afs[64][64];
    __shared__ __align__(16) short Bsh[128][64];
    const int t = threadIdx.x;
    const int lane = t & 63;
    const int w = t >> 6;
    const int wr = w >> 1, wc = w & 1;
    const int r = lane & 15, q = lane >> 4;

    const int L = blockIdx.x;
    const int x = L & 7, j5 = L >> 3;
    const int bx = j5 & 7;
    const int rt = (j5 >> 3) * 8 + x;
    const int brow = rt * 64;

    f32x4 acc[2][4];
#pragma unroll
    for (int m = 0; m < 2; ++m)
#pragma unroll
        for (int n = 0; n < 4; ++n) acc[m][n] = (f32x4)(0.0f);

    for (int kt = 0; kt < 16; ++kt) {
#pragma unroll
        for (int i = 0; i < 4; ++i) {
            int chunk = i * 256 + t;
            int rl = chunk >> 4, d = chunk & 15;
            int cs = d ^ (rl & 7);
            const float* g = kv + (size_t)(brow + rl) * D_MODEL + kt * 64 + cs * 4;
            __builtin_amdgcn_global_load_lds(
                (const __attribute__((address_space(1))) void*)g,
                (__attribute__((address_space(3))) void*)
                    ((char*)&Afs[0][0] + i * 4096 + w * 1024),
                16, 0, 0);
        }
#pragma unroll
        for (int i = 0; i < 4; ++i) {
            int chunk = i * 256 + t;
            int rl = chunk >> 3, d = chunk & 7;
            int cs = d ^ (rl & 7);
            const short* g = Cw + (size_t)(bx * 128 + rl) * D_MODEL + kt * 64 + cs * 8;
            __builtin_amdgcn_global_load_lds(
                (const __attribute__((address_space(1))) void*)g,
                (__attribute__((address_space(3))) void*)
                    ((char*)&Bsh[0][0] + i * 4096 + w * 1024),
                16, 0, 0);
        }
        __syncthreads();
#pragma unroll
        for (int s = 0; s < 2; ++s) {
            short8 af[2], bfr[4];
#pragma unroll
            for (int m = 0; m < 2; ++m) {
                int row = wr * 32 + m * 16 + r;
                int c0 = (s * 8 + q * 2) ^ (row & 7);
                int c1 = (s * 8 + q * 2 + 1) ^ (row & 7);
                float4 lo = *(const float4*)&Afs[row][c0 * 4];
                float4 hi = *(const float4*)&Afs[row][c1 * 4];
                af[m] = cvt8(lo, hi);
            }
#pragma unroll
            for (int n = 0; n < 4; ++n) {
                int row = wc * 64 + n * 16 + r;
                int c = (s * 4 + q) ^ (row & 7);
                bfr[n] = *reinterpret_cast<const short8*>(&Bsh[row][c * 8]);
            }
#pragma unroll
            for (int m = 0; m < 2; ++m)
#pragma unroll
                for (int n = 0; n < 4; ++n)
                    acc[m][n] = __builtin_amdgcn_mfma_f32_16x16x32_bf16(
                        af[m], bfr[n], acc[m][n], 0, 0, 0);
        }
        __syncthreads();
    }

#pragma unroll
    for (int n = 0; n < 4; ++n) {
        int o = bx * 128 + wc * 64 + n * 16 + r;
        float bov = bo[o];
#pragma unroll
        for (int m = 0; m < 2; ++m) {
            int gb = brow + wr * 32 + m * 16 + q * 4;
#pragma unroll
            for (int j = 0; j < 4; ++j) {
                int grow = gb + j;
                out[(size_t)grow * D_MODEL + o] =
                    acc[m][n][j] + bov +
                    query[(size_t)(grow & (BATCH - 1)) * D_MODEL + o];
            }
        }
    }
}

extern "C" void kernel_launch(void* const* d_in, const int* in_sizes, int n_in,
                              void* d_out, int out_size, void* d_ws, size_t ws_size,
                              hipStream_t stream) {
    int kv_i = 1, q_i = 0, bo_i = 6;
    int w_i[4] = {2, 3, 4, 5};
    int nw = 0;
    for (int i = 0; i < n_in; ++i) {
        long s = in_sizes[i];
        if (s == 33554432) kv_i = i;
        else if (s == 4194304) q_i = i;
        else if (s == 1024) bo_i = i;
        else if (s == 1048576 && nw < 4) w_i[nw++] = i;
    }
    const float* query = (const float*)d_in[q_i];
    const float* kv    = (const float*)d_in[kv_i];
    const float* Wv    = (const float*)d_in[w_i[2]];
    const float* Wo    = (const float*)d_in[w_i[3]];
    const float* bo    = (const float*)d_in[bo_i];
    short* Cw  = (short*)d_ws;                          // 2 MB
    float* out = (float*)d_out;

    const size_t need = (size_t)2 * 1024 * 1024 + (size_t)M_ROWS * D_MODEL * 2;
    if (ws_size >= need) {
        short* kvb = (short*)((char*)d_ws + 2 * 1024 * 1024);   // 67 MB
        pre_kernel<<<dim3(2304), dim3(256), 0, stream>>>(Wo, Wv, Cw, kv, kvb);
        attn_gemm_bf16<<<dim3(2048), dim3(256), 0, stream>>>(kvb, query, Cw, bo, out);
    } else {
        pre_kernel<<<dim3(256), dim3(256), 0, stream>>>(Wo, Wv, Cw, kv, nullptr);
        attn_gemm_f32<<<dim3(4096), dim3(256), 0, stream>>>(kv, query, Cw, bo, out);
    }
}